// Round 7
// baseline (198.385 us; speedup 1.0000x reference)
//
#include <hip/hip_runtime.h>
#include <stdint.h>

#define BB    2048
#define DIN   4096
#define DOUT  4096

// ---------------------------------------------------------------------------
// i8 MFMA bit-GEMM. x,m -> ±1 int8; dot± = 2*sums - 4096;
// out = sums > thr  <=>  dot± > 2*thr - 4096. Exact in i32.
//
// R15: FRAGMENT-MAJOR layout + zero-LDS bgemm. Five LDS-staged schedule
// variants (R8-R14) all hit a 46.8us floor: staging writes + b128 quad-
// conflict reads (~61Kcyc/CU) + one block rendezvous per chunk (burst
// alternation, wall~sum). Since WE pack both operands, pack_all now emits
// fragment-major: chunk (rb,kp) = 1KB = rows rb*32..+31 x k[kp*32,+32),
// lane l <-> (row l&31, k-half l>>5) -- the R7-verified MFMA operand map.
// bgemm loads every fragment global->VGPR as ONE coalesced 1KB dwordx4:
// no LDS, no barriers, no conflicts, no split-K. 1024 independent waves
// (1/SIMD), wave tile 128x64, acc[4][2], 24 loads + 32 MFMA per 128B
// k-slice pair..., reg-prefetch 1 slice ahead. Inputs 24MB = L3-resident.
// MFMA floor 15.6us; VMEM 768cyc/chunk < MFMA 1171 -> MFMA-bound.
// ws: x8f frag-major [rb 64][kp 128][1024B] @0 (8 MB);
//     m8Tf frag-major [nb 128][kp 128][1024B] @8MB (16 MB).
// ---------------------------------------------------------------------------

using v4i  = __attribute__((ext_vector_type(4)))  int;
using v16i = __attribute__((ext_vector_type(16))) int;

// bytes {0,1} -> {+1, -1(0xFF)}; no cross-byte carries.
__device__ __forceinline__ unsigned int to_pm1(unsigned int c) {
    return c + ((c ^ 0x01010101u) * 255u);
}

// Fused packing.
// blocks [0,BB): x int32 {0,1} row -> x8f frag-major bytes.
// blocks [BB, BB+1024): 64(n) x 256(k) LDS transpose of masks -> m8Tf.
__global__ void pack_all(const int* __restrict__ x,
                         const void* __restrict__ mraw,
                         char* __restrict__ x8f,
                         char* __restrict__ m8Tf) {
    const int tid = threadIdx.x;
    if (blockIdx.x < BB) {
        const int row = blockIdx.x;
        const int rb  = row >> 5;
        const int rl  = row & 31;
        const int4* src = (const int4*)(x + (size_t)row * DIN);
        #pragma unroll
        for (int q = 0; q < 4; ++q) {
            int4 v = src[q * 256 + tid];           // coalesced 16B/lane
            unsigned int t = (unsigned int)(v.x & 1) |
                             ((unsigned int)(v.y & 1) << 8) |
                             ((unsigned int)(v.z & 1) << 16) |
                             ((unsigned int)(v.w & 1) << 24);
            // word w covers k = 4w..4w+3: frag chunk (rb, kp=w>>3),
            // lane = rl + 32*((w>>2)&1), byte 4*(w&3).
            const int w   = q * 256 + tid;
            const int off = rb * 131072 + (w >> 3) * 1024 +
                            (rl + 32 * ((w >> 2) & 1)) * 16 + 4 * (w & 3);
            *(unsigned int*)(x8f + off) = to_pm1(t);
        }
    } else {
        const int bw = blockIdx.x - BB;            // 0..1023
        const int n0 = (bw >> 4) * 64;             // 64 n-tiles
        const int k0 = (bw & 15) * 256;            // 16 k-strips of 256

        __shared__ unsigned int tl[64][68];        // [n][k-word], pad 68

        // dtype detect (u8-bool vs int32), exact: int32 words are {0,1};
        // u8-bool words exceed 1 unless bytes 1-3 all zero (P ~ 8^-64/wave).
        const unsigned char* mb = (const unsigned char*)mraw;
        const unsigned int pv = *(const unsigned int*)(mb + (tid & 63) * 4);
        const bool isU8 = __any(pv > 1u);

        // stage 1: thread reads 4 k-rows x 16 n-cols (16B/lane coalesced).
        const int kq4  = tid >> 2;                 // 0..63: k-quad index
        const int nq16 = (tid & 3) * 16;           // n-group base
        unsigned int b[4][4];                      // [k-row r][n-word w]
        if (isU8) {
            #pragma unroll
            for (int r = 0; r < 4; ++r) {
                uint4 v = *(const uint4*)(mb + (size_t)(k0 + kq4 * 4 + r) * DOUT
                                          + n0 + nq16);
                b[r][0] = v.x; b[r][1] = v.y; b[r][2] = v.z; b[r][3] = v.w;
            }
        } else {
            const int4* m32 = (const int4*)mraw;
            #pragma unroll
            for (int r = 0; r < 4; ++r)
                #pragma unroll
                for (int q = 0; q < 4; ++q) {
                    int4 v = m32[((size_t)(k0 + kq4 * 4 + r) * DOUT
                                  + n0 + nq16 + q * 4) >> 2];
                    b[r][q] = (unsigned int)(v.x & 1) |
                              ((unsigned int)(v.y & 1) << 8) |
                              ((unsigned int)(v.z & 1) << 16) |
                              ((unsigned int)(v.w & 1) << 24);
                }
        }
        // transpose each 4x4 byte block via v_perm (verified recipe), ±1,
        // write n-major into LDS: word [n][kq4] = bytes k=k0+kq4*4..+3.
        #pragma unroll
        for (int w = 0; w < 4; ++w) {
            unsigned int a0 = b[0][w], a1 = b[1][w], a2 = b[2][w], a3 = b[3][w];
            unsigned int x0 = __builtin_amdgcn_perm(a1, a0, 0x05010400u);
            unsigned int x1 = __builtin_amdgcn_perm(a3, a2, 0x05010400u);
            unsigned int x2 = __builtin_amdgcn_perm(a1, a0, 0x07030602u);
            unsigned int x3 = __builtin_amdgcn_perm(a3, a2, 0x07030602u);
            unsigned int c0 = __builtin_amdgcn_perm(x1, x0, 0x05040100u);
            unsigned int c1 = __builtin_amdgcn_perm(x1, x0, 0x07060302u);
            unsigned int c2 = __builtin_amdgcn_perm(x3, x2, 0x05040100u);
            unsigned int c3 = __builtin_amdgcn_perm(x3, x2, 0x07060302u);
            tl[nq16 + w * 4 + 0][kq4] = to_pm1(c0);
            tl[nq16 + w * 4 + 1][kq4] = to_pm1(c1);
            tl[nq16 + w * 4 + 2][kq4] = to_pm1(c2);
            tl[nq16 + w * 4 + 3][kq4] = to_pm1(c3);
        }
        __syncthreads();

        // stage 2: frag-major out. Wave wv writes chunks idx = wv*4+j:
        // nb-local = idx>>3, kp-local = idx&7. Lane l holds
        // (n = nb*32 + (l&31), k-half l>>5) -> 16B; 64 lanes = 1KB coalesced.
        const int l  = tid & 63;
        const int wvp = tid >> 6;
        #pragma unroll
        for (int j = 0; j < 4; ++j) {
            const int idxc = wvp * 4 + j;          // 0..15
            const int nbl  = idxc >> 3;            // 0..1
            const int kpl  = idxc & 7;             // 0..7
            uint4 v = *(const uint4*)&tl[nbl * 32 + (l & 31)]
                                       [kpl * 8 + (l >> 5) * 4];
            const size_t off = (size_t)((n0 >> 5) + nbl) * 131072 +
                               (size_t)((k0 >> 5) + kpl) * 1024 + l * 16;
            *(uint4*)(m8Tf + off) = v;
        }
    }
}

// Zero-LDS i8 MFMA GEMM. 256 blocks x 256 threads; block tile 256(m)x128(n),
// 4 waves = 2m x 2n, wave tile 128x64 (acc[4][2]), full K per wave.
// Per k-slice p (32 bytes of K): 6 coalesced 1KB frag loads + 8 MFMA.
// Register double-rotation prefetches slice p+1 during slice p's MFMAs.
// No LDS, no barriers, no atomics. 1024 waves = 1/SIMD chip-wide.
__global__ __launch_bounds__(256)
void bgemm(const char* __restrict__ x8f,
           const char* __restrict__ m8Tf,
           const int* __restrict__ thr,
           int* __restrict__ out) {
    // XCD-aware swizzle (R11's): flat%8 = XCD; each XCD a 4m x 8n patch.
    const int flat = blockIdx.x;                   // 0..255
    const int xcd  = flat & 7;
    const int idx  = flat >> 3;                    // 0..31
    const int bm   = (xcd & 1) * 4 + (idx & 3);    // 0..7
    const int bn   = (xcd >> 1) * 8 + (idx >> 2);  // 0..31

    const int tid  = threadIdx.x;
    const int lane = tid & 63;
    const int wv   = tid >> 6;           // 0..3
    const int im   = wv & 1;
    const int in_  = wv >> 1;
    const int mrow0 = bm * 256 + im * 128;
    const int n0w   = bn * 128 + in_ * 64;
    const int l31  = lane & 31;
    const int lh   = lane >> 5;

    const char* Ab = x8f  + (size_t)(mrow0 >> 5) * 131072 + lane * 16;
    const char* Bb = m8Tf + (size_t)(n0w  >> 5) * 131072 + lane * 16;

    v16i acc[4][2];
    #pragma unroll
    for (int t = 0; t < 4; ++t)
        #pragma unroll
        for (int u = 0; u < 2; ++u)
            acc[t][u] = (v16i)(0);

    v4i aC[4], bC[2], aN[4], bN[2];

    #define LD(p, a, b)                                                      \
        {                                                                    \
            _Pragma("unroll")                                                \
            for (int t = 0; t < 4; ++t)                                      \
                (a)[t] = *(const v4i*)(Ab + (size_t)t * 131072 + (p) * 1024);\
            _Pragma("unroll")                                                \
            for (int u = 0; u < 2; ++u)                                      \
                (b)[u] = *(const v4i*)(Bb + (size_t)u * 131072 + (p) * 1024);\
        }
    #define MM(a, b)                                                         \
        {                                                                    \
            _Pragma("unroll")                                                \
            for (int t = 0; t < 4; ++t)                                      \
                _Pragma("unroll")                                            \
                for (int u = 0; u < 2; ++u)                                  \
                    acc[t][u] = __builtin_amdgcn_mfma_i32_32x32x32_i8(       \
                        (a)[t], (b)[u], acc[t][u], 0, 0, 0);                 \
        }

    LD(0, aC, bC);
    for (int p = 0; p < 128; p += 2) {
        LD(p + 1, aN, bN);
        MM(aC, bC);
        if (p + 2 < 128) LD(p + 2, aC, bC);
        MM(aN, bN);
    }
    #undef LD
    #undef MM

    // epilogue: out = (dot± > 2*thr - 4096).
    // C/D layout (verified R7): col = lane&31; row = (reg&3)+8*(reg>>2)+4*(lane>>5).
    #pragma unroll
    for (int u = 0; u < 2; ++u) {
        const int o   = n0w + u * 32 + l31;
        const int lim = 2 * thr[o] - DIN;
        #pragma unroll
        for (int t = 0; t < 4; ++t) {
            #pragma unroll
            for (int r = 0; r < 16; ++r) {
                const int rowl = (r & 3) + 8 * (r >> 2) + 4 * lh;
                const int b    = mrow0 + t * 32 + rowl;
                out[(size_t)b * DOUT + o] = (acc[t][u][r] > lim) ? 1 : 0;
            }
        }
    }
}

extern "C" void kernel_launch(void* const* d_in, const int* in_sizes, int n_in,
                              void* d_out, int out_size, void* d_ws, size_t ws_size,
                              hipStream_t stream) {
    const int* x          = (const int*)d_in[0];
    const void* masks     = d_in[1];           // bool: u8 or int32 (detected inline)
    const int* thresholds = (const int*)d_in[2];
    int* out              = (int*)d_out;

    char* x8f  = (char*)d_ws;                         // 8 MB frag-major
    char* m8Tf = (char*)d_ws + ((size_t)8 << 20);     // 16 MB frag-major

    pack_all<<<BB + 1024, 256, 0, stream>>>(x, masks, x8f, m8Tf);
    bgemm<<<256, 256, 0, stream>>>(x8f, m8Tf, thresholds, out);
}

// Round 8
// 175.702 us; speedup vs baseline: 1.1291x; 1.1291x over previous
//
#include <hip/hip_runtime.h>
#include <stdint.h>

#define BB    2048
#define DIN   4096
#define DOUT  4096

// ---------------------------------------------------------------------------
// i8 MFMA bit-GEMM. x,m -> ±1 int8; dot± = 2*sums - 4096;
// out = sums > thr  <=>  dot± > 2*thr - 4096. Exact in i32.
//
// R15 post-mortem: zero-LDS refuted (64us, MfmaUtil 19.6, VALU 6%): no
// on-CU reuse -> 768MB L2/L3 traffic (2x LDS version) + 1 wave/SIMD can't
// hide L3 latency. But the FRAG-MAJOR global layout is verified (absmax 0)
// and enables the clean hybrid:
// R16 = R11 schedule (46.8us: 256x128, 8 waves 2m x 2n x 2k, BK=128,
// triple-buffer 144KB, depth-2 prefetch, vmcnt(6), ONE barrier/chunk,
// LDS split-K combine) + frag-major LDS chunks. Both LDS sides now LINEAR:
// global_load_lds stages whole 1KB chunks (its native base+lane*16), and
// each MFMA fragment read is a contiguous 1KB ds_read_b128 at lane*16 ->
// conflict-free 12cyc/KB vs the old column-gather's 4-way quad 16cyc/KB.
// Predict: SQ_LDS_BANK_CONFLICT 3.15M -> ~0, bgemm 46.8 -> 38-42us.
// ws: x8f frag-major [rb 64][kp 128][1024B] @0 (8 MB);
//     m8Tf frag-major [nb 128][kp 128][1024B] @8MB (16 MB).
// chunk(rb,kp): rows rb*32..+31, k bytes [kp*32,+32); lane l = row l&31,
// k-half l>>5, 16B -- the R7-verified mfma_i32_32x32x32_i8 operand map.
// ---------------------------------------------------------------------------

using v4i  = __attribute__((ext_vector_type(4)))  int;
using v16i = __attribute__((ext_vector_type(16))) int;

__device__ __forceinline__ void async_load16(const void* g, void* l) {
    __builtin_amdgcn_global_load_lds(
        (const __attribute__((address_space(1))) unsigned int*)g,
        (__attribute__((address_space(3))) unsigned int*)l,
        16, 0, 0);
}

// bytes {0,1} -> {+1, -1(0xFF)}; no cross-byte carries.
__device__ __forceinline__ unsigned int to_pm1(unsigned int c) {
    return c + ((c ^ 0x01010101u) * 255u);
}

// Fused packing (R15 verbatim, verified absmax 0).
// blocks [0,BB): x int32 {0,1} row -> x8f frag-major bytes.
// blocks [BB, BB+1024): 64(n) x 256(k) LDS transpose of masks -> m8Tf.
__global__ void pack_all(const int* __restrict__ x,
                         const void* __restrict__ mraw,
                         char* __restrict__ x8f,
                         char* __restrict__ m8Tf) {
    const int tid = threadIdx.x;
    if (blockIdx.x < BB) {
        const int row = blockIdx.x;
        const int rb  = row >> 5;
        const int rl  = row & 31;
        const int4* src = (const int4*)(x + (size_t)row * DIN);
        #pragma unroll
        for (int q = 0; q < 4; ++q) {
            int4 v = src[q * 256 + tid];           // coalesced 16B/lane
            unsigned int t = (unsigned int)(v.x & 1) |
                             ((unsigned int)(v.y & 1) << 8) |
                             ((unsigned int)(v.z & 1) << 16) |
                             ((unsigned int)(v.w & 1) << 24);
            // word w covers k = 4w..4w+3: frag chunk (rb, kp=w>>3),
            // lane = rl + 32*((w>>2)&1), byte 4*(w&3).
            const int w   = q * 256 + tid;
            const int off = rb * 131072 + (w >> 3) * 1024 +
                            (rl + 32 * ((w >> 2) & 1)) * 16 + 4 * (w & 3);
            *(unsigned int*)(x8f + off) = to_pm1(t);
        }
    } else {
        const int bw = blockIdx.x - BB;            // 0..1023
        const int n0 = (bw >> 4) * 64;             // 64 n-tiles
        const int k0 = (bw & 15) * 256;            // 16 k-strips of 256

        __shared__ unsigned int tl[64][68];        // [n][k-word], pad 68

        // dtype detect (u8-bool vs int32), exact: int32 words are {0,1};
        // u8-bool words exceed 1 unless bytes 1-3 all zero (P ~ 8^-64/wave).
        const unsigned char* mb = (const unsigned char*)mraw;
        const unsigned int pv = *(const unsigned int*)(mb + (tid & 63) * 4);
        const bool isU8 = __any(pv > 1u);

        // stage 1: thread reads 4 k-rows x 16 n-cols (16B/lane coalesced).
        const int kq4  = tid >> 2;                 // 0..63: k-quad index
        const int nq16 = (tid & 3) * 16;           // n-group base
        unsigned int b[4][4];                      // [k-row r][n-word w]
        if (isU8) {
            #pragma unroll
            for (int r = 0; r < 4; ++r) {
                uint4 v = *(const uint4*)(mb + (size_t)(k0 + kq4 * 4 + r) * DOUT
                                          + n0 + nq16);
                b[r][0] = v.x; b[r][1] = v.y; b[r][2] = v.z; b[r][3] = v.w;
            }
        } else {
            const int4* m32 = (const int4*)mraw;
            #pragma unroll
            for (int r = 0; r < 4; ++r)
                #pragma unroll
                for (int q = 0; q < 4; ++q) {
                    int4 v = m32[((size_t)(k0 + kq4 * 4 + r) * DOUT
                                  + n0 + nq16 + q * 4) >> 2];
                    b[r][q] = (unsigned int)(v.x & 1) |
                              ((unsigned int)(v.y & 1) << 8) |
                              ((unsigned int)(v.z & 1) << 16) |
                              ((unsigned int)(v.w & 1) << 24);
                }
        }
        // transpose each 4x4 byte block via v_perm (verified recipe), ±1,
        // write n-major into LDS: word [n][kq4] = bytes k=k0+kq4*4..+3.
        #pragma unroll
        for (int w = 0; w < 4; ++w) {
            unsigned int a0 = b[0][w], a1 = b[1][w], a2 = b[2][w], a3 = b[3][w];
            unsigned int x0 = __builtin_amdgcn_perm(a1, a0, 0x05010400u);
            unsigned int x1 = __builtin_amdgcn_perm(a3, a2, 0x05010400u);
            unsigned int x2 = __builtin_amdgcn_perm(a1, a0, 0x07030602u);
            unsigned int x3 = __builtin_amdgcn_perm(a3, a2, 0x07030602u);
            unsigned int c0 = __builtin_amdgcn_perm(x1, x0, 0x05040100u);
            unsigned int c1 = __builtin_amdgcn_perm(x1, x0, 0x07060302u);
            unsigned int c2 = __builtin_amdgcn_perm(x3, x2, 0x05040100u);
            unsigned int c3 = __builtin_amdgcn_perm(x3, x2, 0x07060302u);
            tl[nq16 + w * 4 + 0][kq4] = to_pm1(c0);
            tl[nq16 + w * 4 + 1][kq4] = to_pm1(c1);
            tl[nq16 + w * 4 + 2][kq4] = to_pm1(c2);
            tl[nq16 + w * 4 + 3][kq4] = to_pm1(c3);
        }
        __syncthreads();

        // stage 2: frag-major out. Wave wv writes chunks idx = wv*4+j:
        // nb-local = idx>>3, kp-local = idx&7. Lane l holds
        // (n = nb*32 + (l&31), k-half l>>5) -> 16B; 64 lanes = 1KB coalesced.
        const int l  = tid & 63;
        const int wvp = tid >> 6;
        #pragma unroll
        for (int j = 0; j < 4; ++j) {
            const int idxc = wvp * 4 + j;          // 0..15
            const int nbl  = idxc >> 3;            // 0..1
            const int kpl  = idxc & 7;             // 0..7
            uint4 v = *(const uint4*)&tl[nbl * 32 + (l & 31)]
                                       [kpl * 8 + (l >> 5) * 4];
            const size_t off = (size_t)((n0 >> 5) + nbl) * 131072 +
                               (size_t)((k0 >> 5) + kpl) * 1024 + l * 16;
            *(uint4*)(m8Tf + off) = v;
        }
    }
}

// i8 MFMA GEMM (R11 schedule + frag-major LDS): 256(m)x128(n) block tile,
// 8 waves = 2m x 2n x 2k(split-K), wave tile 128x64 (acc[4][2]). BK=128
// chunks (32), triple-buffer LDS (144 KB), depth-2 prefetch, one raw
// s_barrier per chunk with counted vmcnt(6). Split-K combine via LDS pool.
// LDS: bufA = 32 chunks (rb 8 x kp 4), bufB = 16 chunks (nb 4 x kp 4);
// every stage write and frag read is a LINEAR 1KB at lane*16.
__global__ __launch_bounds__(512)
void bgemm(const char* __restrict__ x8f,
           const char* __restrict__ m8Tf,
           const int* __restrict__ thr,
           int* __restrict__ out) {
    // XCD-aware swizzle: flat%8 = XCD; each XCD a compact 4m x 8n patch.
    const int flat = blockIdx.x;                   // 0..255
    const int xcd  = flat & 7;
    const int idx  = flat >> 3;                    // 0..31
    const int bm   = (xcd & 1) * 4 + (idx & 3);    // 0..7
    const int bn   = (xcd >> 1) * 8 + (idx >> 2);  // 0..31
    const int b0   = bm * 256;                     // m
    const int o0   = bn * 128;                     // n

    const int tid  = threadIdx.x;
    const int lane = tid & 63;
    const int wv   = tid >> 6;           // 0..7
    const int im   = wv & 1;
    const int in_  = (wv >> 1) & 1;
    const int kh   = wv >> 2;            // split-K half
    const int wm   = im * 128;           // wave tile m origin
    const int wn   = in_ * 64;           // wave tile n origin
    const int l31  = lane & 31;
    const int lh   = lane >> 5;

    // 3 buffers x (A 32KB + B 16KB) = 144 KB; pool reused for split-K combine.
    __shared__ __align__(16) char lds[3 * 49152];

    // stage chunk-step c -> buf: 48 x 1KB frag chunks, all linear.
    // 6 global_load_lds per thread (A:4, B:2) -- vmcnt schedule = R11.
    auto stage = [&](int c, int buf) {
        char* bufA = lds + buf * 49152;
        char* bufB = bufA + 32768;
        const int kp0 = c * 4;
        #pragma unroll
        for (int j = 0; j < 4; ++j) {              // A: 4 chunks/wave
            const int ci = wv * 4 + j;             // 0..31
            const int rb = ci >> 2, kp = ci & 3;
            async_load16(x8f + (size_t)(bm * 8 + rb) * 131072 +
                               (size_t)(kp0 + kp) * 1024 + lane * 16,
                         bufA + ci * 1024 + lane * 16);
        }
        #pragma unroll
        for (int j = 0; j < 2; ++j) {              // B: 2 chunks/wave
            const int ci = wv * 2 + j;             // 0..15
            const int nb = ci >> 2, kp = ci & 3;
            async_load16(m8Tf + (size_t)(bn * 4 + nb) * 131072 +
                                (size_t)(kp0 + kp) * 1024 + lane * 16,
                         bufB + ci * 1024 + lane * 16);
        }
    };

    v16i acc[4][2];
    #pragma unroll
    for (int t = 0; t < 4; ++t)
        #pragma unroll
        for (int u = 0; u < 2; ++u)
            acc[t][u] = (v16i)(0);

    // prologue: depth-2 prefetch (12 loads/thread in flight).
    stage(0, 0);
    stage(1, 1);

    for (int c = 0; c < 32; ++c) {
        // drain exactly stage(c): leave stage(c+1) (6 loads) in flight.
        if (c < 31) asm volatile("s_waitcnt vmcnt(6)" ::: "memory");
        else        asm volatile("s_waitcnt vmcnt(0)" ::: "memory");
        __builtin_amdgcn_s_barrier();  // stage(c) visible everywhere; all
                                       // waves done computing c-1 -> buf free
        if (c < 30) stage(c + 2, (c + 2) % 3);

        const char* bufA = lds + (c % 3) * 49152;
        const char* bufB = bufA + 32768;
        #pragma unroll
        for (int ks = 0; ks < 2; ++ks) {
            const int kp = kh * 2 + ks;            // this wave's kp chunk
            v4i aF[4], bF[2];
            #pragma unroll
            for (int t = 0; t < 4; ++t)
                aF[t] = *(const v4i*)&bufA[((im * 4 + t) * 4 + kp) * 1024
                                           + lane * 16];
            #pragma unroll
            for (int u = 0; u < 2; ++u)
                bF[u] = *(const v4i*)&bufB[((in_ * 2 + u) * 4 + kp) * 1024
                                           + lane * 16];
            #pragma unroll
            for (int t = 0; t < 4; ++t)
                #pragma unroll
                for (int u = 0; u < 2; ++u)
                    acc[t][u] = __builtin_amdgcn_mfma_i32_32x32x32_i8(
                        aF[t], bF[u], acc[t][u], 0, 0, 0);
        }
    }
    __syncthreads();   // all compute done; lds pool free for combine

    // ---- split-K combine. Pair p = (im,in_): waves (p, kh=0) and (p, kh=1)
    // computed the same 128x64 tile over disjoint K halves. Each wave gives
    // one 64-row half via LDS and keeps the other: h=0 keeps t0,1 gives t2,3;
    // h=1 keeps t2,3 gives t0,1. Pool: per pair 8192 i32 (2 halves x 4096).
    int* pool = (int*)lds;                         // 128 KB used
    const int p = wv & 3;
    {
        const int give0 = kh ? 0 : 2;              // first given t
        const int bw_ = p * 8192 + (kh ? 0 : 1) * 4096;
        #pragma unroll
        for (int tt = 0; tt < 2; ++tt) {
            const int t = give0 + tt;
            #pragma unroll
            for (int u = 0; u < 2; ++u)
                #pragma unroll
                for (int r = 0; r < 16; ++r) {
                    const int rowl = (r & 3) + 8 * (r >> 2) + 4 * lh;
                    pool[bw_ + (tt * 32 + rowl) * 64 + u * 32 + l31] = acc[t][u][r];
                }
        }
    }
    __syncthreads();
    const int keep0 = kh ? 2 : 0;
    const int br_ = p * 8192 + kh * 4096;          // partner's gift = my kept rows
    #pragma unroll
    for (int tt = 0; tt < 2; ++tt) {
        const int t = keep0 + tt;
        #pragma unroll
        for (int u = 0; u < 2; ++u)
            #pragma unroll
            for (int r = 0; r < 16; ++r) {
                const int rowl = (r & 3) + 8 * (r >> 2) + 4 * lh;
                acc[t][u][r] += pool[br_ + (tt * 32 + rowl) * 64 + u * 32 + l31];
            }
    }

    // epilogue: out = (dot± > 2*thr - 4096).
    // C/D layout (verified R7): col = lane&31; row = (reg&3)+8*(reg>>2)+4*(lane>>5).
    #pragma unroll
    for (int u = 0; u < 2; ++u) {
        const int o   = o0 + wn + u * 32 + l31;
        const int lim = 2 * thr[o] - DIN;
        #pragma unroll
        for (int tt = 0; tt < 2; ++tt) {
            const int t = keep0 + tt;
            #pragma unroll
            for (int r = 0; r < 16; ++r) {
                const int rowl = (r & 3) + 8 * (r >> 2) + 4 * lh;
                const int b    = b0 + wm + kh * 64 + tt * 32 + rowl;
                out[(size_t)b * DOUT + o] = (acc[t][u][r] > lim) ? 1 : 0;
            }
        }
    }
}

extern "C" void kernel_launch(void* const* d_in, const int* in_sizes, int n_in,
                              void* d_out, int out_size, void* d_ws, size_t ws_size,
                              hipStream_t stream) {
    const int* x          = (const int*)d_in[0];
    const void* masks     = d_in[1];           // bool: u8 or int32 (detected inline)
    const int* thresholds = (const int*)d_in[2];
    int* out              = (int*)d_out;

    char* x8f  = (char*)d_ws;                         // 8 MB frag-major
    char* m8Tf = (char*)d_ws + ((size_t)8 << 20);     // 16 MB frag-major

    pack_all<<<BB + 1024, 256, 0, stream>>>(x, masks, x8f, m8Tf);
    bgemm<<<256, 512, 0, stream>>>(x8f, m8Tf, thresholds, out);
}

// Round 9
// 173.305 us; speedup vs baseline: 1.1447x; 1.0138x over previous
//
#include <hip/hip_runtime.h>
#include <stdint.h>

#define BB    2048
#define DIN   4096
#define DOUT  4096

// ---------------------------------------------------------------------------
// i8 MFMA bit-GEMM. x,m -> ±1 int8; dot± = 2*sums - 4096;
// out = sums > thr  <=>  dot± > 2*thr - 4096. Exact in i32.
//
// R16 post-mortem: bgemm (frag-major LDS, conflict-free) dropped below
// pack_all (45.6us, 1.84TB/s, VALU 5.5%) -- pack is now co-bottleneck,
// transaction-bound: R15's x-branch emitted 4 scattered 4B stores/thread
// (w = q*256+tid puts a thread's words in 4 different chunks). R17: remap
// w = tid*4+q -> thread's 16 k-values = exactly ONE 16B frag slot ->
// register-assemble + single uint4 store (4x fewer, wider stores); loads
// 4x int4 @64B stride (same lines, L1-hit). Mask branch + bgemm = R16
// verbatim. Predict pack 45.6 -> 22-30us, bgemm ~44 unchanged.
// ws: x8f frag-major [rb 64][kp 128][1024B] @0 (8 MB);
//     m8Tf frag-major [nb 128][kp 128][1024B] @8MB (16 MB).
// chunk(rb,kp): rows rb*32..+31, k bytes [kp*32,+32); lane l = row l&31,
// k-half l>>5, 16B -- the R7-verified mfma_i32_32x32x32_i8 operand map.
// ---------------------------------------------------------------------------

using v4i  = __attribute__((ext_vector_type(4)))  int;
using v16i = __attribute__((ext_vector_type(16))) int;

__device__ __forceinline__ void async_load16(const void* g, void* l) {
    __builtin_amdgcn_global_load_lds(
        (const __attribute__((address_space(1))) unsigned int*)g,
        (__attribute__((address_space(3))) unsigned int*)l,
        16, 0, 0);
}

// bytes {0,1} -> {+1, -1(0xFF)}; no cross-byte carries.
__device__ __forceinline__ unsigned int to_pm1(unsigned int c) {
    return c + ((c ^ 0x01010101u) * 255u);
}

// Fused packing.
// blocks [0,BB): x int32 {0,1} row -> x8f frag-major bytes (R17 remap:
//   thread tid owns k [tid*16,+16) = one 16B slot -> one uint4 store).
// blocks [BB, BB+1024): 64(n) x 256(k) LDS transpose of masks -> m8Tf.
__global__ void pack_all(const int* __restrict__ x,
                         const void* __restrict__ mraw,
                         char* __restrict__ x8f,
                         char* __restrict__ m8Tf) {
    const int tid = threadIdx.x;
    if (blockIdx.x < BB) {
        const int row = blockIdx.x;
        const int rb  = row >> 5;
        const int rl  = row & 31;
        const int4* src = (const int4*)(x + (size_t)row * DIN);
        unsigned int t[4];
        #pragma unroll
        for (int q = 0; q < 4; ++q) {
            int4 v = src[tid * 4 + q];             // 64B/thread run
            t[q] = to_pm1((unsigned int)(v.x & 1) |
                          ((unsigned int)(v.y & 1) << 8) |
                          ((unsigned int)(v.z & 1) << 16) |
                          ((unsigned int)(v.w & 1) << 24));
        }
        // w = tid*4+q covers k = 16*tid..+15: chunk kp = tid>>1,
        // slot lane = rl + 32*(tid&1), bytes 0..15 -- one frag slot.
        const int off = rb * 131072 + (tid >> 1) * 1024 +
                        (rl + 32 * (tid & 1)) * 16;
        uint4 U; U.x = t[0]; U.y = t[1]; U.z = t[2]; U.w = t[3];
        *(uint4*)(x8f + off) = U;
    } else {
        const int bw = blockIdx.x - BB;            // 0..1023
        const int n0 = (bw >> 4) * 64;             // 64 n-tiles
        const int k0 = (bw & 15) * 256;            // 16 k-strips of 256

        __shared__ unsigned int tl[64][68];        // [n][k-word], pad 68

        // dtype detect (u8-bool vs int32), exact: int32 words are {0,1};
        // u8-bool words exceed 1 unless bytes 1-3 all zero (P ~ 8^-64/wave).
        const unsigned char* mb = (const unsigned char*)mraw;
        const unsigned int pv = *(const unsigned int*)(mb + (tid & 63) * 4);
        const bool isU8 = __any(pv > 1u);

        // stage 1: thread reads 4 k-rows x 16 n-cols (16B/lane coalesced).
        const int kq4  = tid >> 2;                 // 0..63: k-quad index
        const int nq16 = (tid & 3) * 16;           // n-group base
        unsigned int b[4][4];                      // [k-row r][n-word w]
        if (isU8) {
            #pragma unroll
            for (int r = 0; r < 4; ++r) {
                uint4 v = *(const uint4*)(mb + (size_t)(k0 + kq4 * 4 + r) * DOUT
                                          + n0 + nq16);
                b[r][0] = v.x; b[r][1] = v.y; b[r][2] = v.z; b[r][3] = v.w;
            }
        } else {
            const int4* m32 = (const int4*)mraw;
            #pragma unroll
            for (int r = 0; r < 4; ++r)
                #pragma unroll
                for (int q = 0; q < 4; ++q) {
                    int4 v = m32[((size_t)(k0 + kq4 * 4 + r) * DOUT
                                  + n0 + nq16 + q * 4) >> 2];
                    b[r][q] = (unsigned int)(v.x & 1) |
                              ((unsigned int)(v.y & 1) << 8) |
                              ((unsigned int)(v.z & 1) << 16) |
                              ((unsigned int)(v.w & 1) << 24);
                }
        }
        // transpose each 4x4 byte block via v_perm (verified recipe), ±1,
        // write n-major into LDS: word [n][kq4] = bytes k=k0+kq4*4..+3.
        #pragma unroll
        for (int w = 0; w < 4; ++w) {
            unsigned int a0 = b[0][w], a1 = b[1][w], a2 = b[2][w], a3 = b[3][w];
            unsigned int x0 = __builtin_amdgcn_perm(a1, a0, 0x05010400u);
            unsigned int x1 = __builtin_amdgcn_perm(a3, a2, 0x05010400u);
            unsigned int x2 = __builtin_amdgcn_perm(a1, a0, 0x07030602u);
            unsigned int x3 = __builtin_amdgcn_perm(a3, a2, 0x07030602u);
            unsigned int c0 = __builtin_amdgcn_perm(x1, x0, 0x05040100u);
            unsigned int c1 = __builtin_amdgcn_perm(x1, x0, 0x07060302u);
            unsigned int c2 = __builtin_amdgcn_perm(x3, x2, 0x05040100u);
            unsigned int c3 = __builtin_amdgcn_perm(x3, x2, 0x07060302u);
            tl[nq16 + w * 4 + 0][kq4] = to_pm1(c0);
            tl[nq16 + w * 4 + 1][kq4] = to_pm1(c1);
            tl[nq16 + w * 4 + 2][kq4] = to_pm1(c2);
            tl[nq16 + w * 4 + 3][kq4] = to_pm1(c3);
        }
        __syncthreads();

        // stage 2: frag-major out. Wave wv writes chunks idx = wv*4+j:
        // nb-local = idx>>3, kp-local = idx&7. Lane l holds
        // (n = nb*32 + (l&31), k-half l>>5) -> 16B; 64 lanes = 1KB coalesced.
        const int l  = tid & 63;
        const int wvp = tid >> 6;
        #pragma unroll
        for (int j = 0; j < 4; ++j) {
            const int idxc = wvp * 4 + j;          // 0..15
            const int nbl  = idxc >> 3;            // 0..1
            const int kpl  = idxc & 7;             // 0..7
            uint4 v = *(const uint4*)&tl[nbl * 32 + (l & 31)]
                                       [kpl * 8 + (l >> 5) * 4];
            const size_t off = (size_t)((n0 >> 5) + nbl) * 131072 +
                               (size_t)((k0 >> 5) + kpl) * 1024 + l * 16;
            *(uint4*)(m8Tf + off) = v;
        }
    }
}

// i8 MFMA GEMM (R16 verbatim: R11 schedule + frag-major LDS): 256(m)x128(n)
// block tile, 8 waves = 2m x 2n x 2k(split-K), wave tile 128x64 (acc[4][2]).
// BK=128 chunks (32), triple-buffer LDS (144 KB), depth-2 prefetch, one raw
// s_barrier per chunk with counted vmcnt(6). Split-K combine via LDS pool.
// LDS: bufA = 32 chunks (rb 8 x kp 4), bufB = 16 chunks (nb 4 x kp 4);
// every stage write and frag read is a LINEAR 1KB at lane*16.
__global__ __launch_bounds__(512)
void bgemm(const char* __restrict__ x8f,
           const char* __restrict__ m8Tf,
           const int* __restrict__ thr,
           int* __restrict__ out) {
    // XCD-aware swizzle: flat%8 = XCD; each XCD a compact 4m x 8n patch.
    const int flat = blockIdx.x;                   // 0..255
    const int xcd  = flat & 7;
    const int idx  = flat >> 3;                    // 0..31
    const int bm   = (xcd & 1) * 4 + (idx & 3);    // 0..7
    const int bn   = (xcd >> 1) * 8 + (idx >> 2);  // 0..31
    const int b0   = bm * 256;                     // m
    const int o0   = bn * 128;                     // n

    const int tid  = threadIdx.x;
    const int lane = tid & 63;
    const int wv   = tid >> 6;           // 0..7
    const int im   = wv & 1;
    const int in_  = (wv >> 1) & 1;
    const int kh   = wv >> 2;            // split-K half
    const int wm   = im * 128;           // wave tile m origin
    const int wn   = in_ * 64;           // wave tile n origin
    const int l31  = lane & 31;
    const int lh   = lane >> 5;

    // 3 buffers x (A 32KB + B 16KB) = 144 KB; pool reused for split-K combine.
    __shared__ __align__(16) char lds[3 * 49152];

    // stage chunk-step c -> buf: 48 x 1KB frag chunks, all linear.
    // 6 global_load_lds per thread (A:4, B:2) -- vmcnt schedule = R11.
    auto stage = [&](int c, int buf) {
        char* bufA = lds + buf * 49152;
        char* bufB = bufA + 32768;
        const int kp0 = c * 4;
        #pragma unroll
        for (int j = 0; j < 4; ++j) {              // A: 4 chunks/wave
            const int ci = wv * 4 + j;             // 0..31
            const int rb = ci >> 2, kp = ci & 3;
            async_load16(x8f + (size_t)(bm * 8 + rb) * 131072 +
                               (size_t)(kp0 + kp) * 1024 + lane * 16,
                         bufA + ci * 1024 + lane * 16);
        }
        #pragma unroll
        for (int j = 0; j < 2; ++j) {              // B: 2 chunks/wave
            const int ci = wv * 2 + j;             // 0..15
            const int nb = ci >> 2, kp = ci & 3;
            async_load16(m8Tf + (size_t)(bn * 4 + nb) * 131072 +
                                (size_t)(kp0 + kp) * 1024 + lane * 16,
                         bufB + ci * 1024 + lane * 16);
        }
    };

    v16i acc[4][2];
    #pragma unroll
    for (int t = 0; t < 4; ++t)
        #pragma unroll
        for (int u = 0; u < 2; ++u)
            acc[t][u] = (v16i)(0);

    // prologue: depth-2 prefetch (12 loads/thread in flight).
    stage(0, 0);
    stage(1, 1);

    for (int c = 0; c < 32; ++c) {
        // drain exactly stage(c): leave stage(c+1) (6 loads) in flight.
        if (c < 31) asm volatile("s_waitcnt vmcnt(6)" ::: "memory");
        else        asm volatile("s_waitcnt vmcnt(0)" ::: "memory");
        __builtin_amdgcn_s_barrier();  // stage(c) visible everywhere; all
                                       // waves done computing c-1 -> buf free
        if (c < 30) stage(c + 2, (c + 2) % 3);

        const char* bufA = lds + (c % 3) * 49152;
        const char* bufB = bufA + 32768;
        #pragma unroll
        for (int ks = 0; ks < 2; ++ks) {
            const int kp = kh * 2 + ks;            // this wave's kp chunk
            v4i aF[4], bF[2];
            #pragma unroll
            for (int t = 0; t < 4; ++t)
                aF[t] = *(const v4i*)&bufA[((im * 4 + t) * 4 + kp) * 1024
                                           + lane * 16];
            #pragma unroll
            for (int u = 0; u < 2; ++u)
                bF[u] = *(const v4i*)&bufB[((in_ * 2 + u) * 4 + kp) * 1024
                                           + lane * 16];
            #pragma unroll
            for (int t = 0; t < 4; ++t)
                #pragma unroll
                for (int u = 0; u < 2; ++u)
                    acc[t][u] = __builtin_amdgcn_mfma_i32_32x32x32_i8(
                        aF[t], bF[u], acc[t][u], 0, 0, 0);
        }
    }
    __syncthreads();   // all compute done; lds pool free for combine

    // ---- split-K combine. Pair p = (im,in_): waves (p, kh=0) and (p, kh=1)
    // computed the same 128x64 tile over disjoint K halves. Each wave gives
    // one 64-row half via LDS and keeps the other: h=0 keeps t0,1 gives t2,3;
    // h=1 keeps t2,3 gives t0,1. Pool: per pair 8192 i32 (2 halves x 4096).
    int* pool = (int*)lds;                         // 128 KB used
    const int p = wv & 3;
    {
        const int give0 = kh ? 0 : 2;              // first given t
        const int bw_ = p * 8192 + (kh ? 0 : 1) * 4096;
        #pragma unroll
        for (int tt = 0; tt < 2; ++tt) {
            const int t = give0 + tt;
            #pragma unroll
            for (int u = 0; u < 2; ++u)
                #pragma unroll
                for (int r = 0; r < 16; ++r) {
                    const int rowl = (r & 3) + 8 * (r >> 2) + 4 * lh;
                    pool[bw_ + (tt * 32 + rowl) * 64 + u * 32 + l31] = acc[t][u][r];
                }
        }
    }
    __syncthreads();
    const int keep0 = kh ? 2 : 0;
    const int br_ = p * 8192 + kh * 4096;          // partner's gift = my kept rows
    #pragma unroll
    for (int tt = 0; tt < 2; ++tt) {
        const int t = keep0 + tt;
        #pragma unroll
        for (int u = 0; u < 2; ++u)
            #pragma unroll
            for (int r = 0; r < 16; ++r) {
                const int rowl = (r & 3) + 8 * (r >> 2) + 4 * lh;
                acc[t][u][r] += pool[br_ + (tt * 32 + rowl) * 64 + u * 32 + l31];
            }
    }

    // epilogue: out = (dot± > 2*thr - 4096).
    // C/D layout (verified R7): col = lane&31; row = (reg&3)+8*(reg>>2)+4*(lane>>5).
    #pragma unroll
    for (int u = 0; u < 2; ++u) {
        const int o   = o0 + wn + u * 32 + l31;
        const int lim = 2 * thr[o] - DIN;
        #pragma unroll
        for (int tt = 0; tt < 2; ++tt) {
            const int t = keep0 + tt;
            #pragma unroll
            for (int r = 0; r < 16; ++r) {
                const int rowl = (r & 3) + 8 * (r >> 2) + 4 * lh;
                const int b    = b0 + wm + kh * 64 + tt * 32 + rowl;
                out[(size_t)b * DOUT + o] = (acc[t][u][r] > lim) ? 1 : 0;
            }
        }
    }
}

extern "C" void kernel_launch(void* const* d_in, const int* in_sizes, int n_in,
                              void* d_out, int out_size, void* d_ws, size_t ws_size,
                              hipStream_t stream) {
    const int* x          = (const int*)d_in[0];
    const void* masks     = d_in[1];           // bool: u8 or int32 (detected inline)
    const int* thresholds = (const int*)d_in[2];
    int* out              = (int*)d_out;

    char* x8f  = (char*)d_ws;                         // 8 MB frag-major
    char* m8Tf = (char*)d_ws + ((size_t)8 << 20);     // 16 MB frag-major

    pack_all<<<BB + 1024, 256, 0, stream>>>(x, masks, x8f, m8Tf);
    bgemm<<<256, 512, 0, stream>>>(x8f, m8Tf, thresholds, out);
}